// Round 6
// baseline (274.152 us; speedup 1.0000x reference)
//
#include <hip/hip_runtime.h>

#define B_   64
#define E_   1024
#define N_   512
#define D_   64
#define HID_ 128
#define T_   5

typedef __bf16 bf16x8 __attribute__((ext_vector_type(8)));
typedef float f32x4 __attribute__((ext_vector_type(4)));

__device__ __forceinline__ unsigned short f2bu(float f) {
    union { float f; unsigned int u; } v; v.f = f;
    unsigned int r = (v.u + 0x7fffu + ((v.u >> 16) & 1u)) >> 16;  // RNE
    return (unsigned short)r;
}

__device__ __forceinline__ unsigned int pack2(float lo, float hi) {
    union { __bf16 b[2]; unsigned int u; } v;
    v.b[0] = (__bf16)lo; v.b[1] = (__bf16)hi;   // RNE
    return v.u;
}

__device__ __forceinline__ uint4 cvt8(float4 a, float4 b) {
    union { __bf16 h[8]; uint4 u; } v;
    v.h[0] = (__bf16)a.x; v.h[1] = (__bf16)a.y; v.h[2] = (__bf16)a.z; v.h[3] = (__bf16)a.w;
    v.h[4] = (__bf16)b.x; v.h[5] = (__bf16)b.y; v.h[6] = (__bf16)b.z; v.h[7] = (__bf16)b.w;
    return v.u;
}

#define MFMA16(a, b, c) __builtin_amdgcn_mfma_f32_16x16x32_bf16((a), (b), (c), 0, 0, 0)

// ---------------------------------------------------------------------------
// Prep: W1[t][d][h] -> W1T[t][h][d] bf16 ; W2[t][h][d] -> W2T[t][d][h] bf16
// ---------------------------------------------------------------------------
__global__ __launch_bounds__(256) void k_prep_w(const float* __restrict__ W1,
                                                const float* __restrict__ W2,
                                                unsigned short* __restrict__ W1T,
                                                unsigned short* __restrict__ W2T) {
    int idx = blockIdx.x * 256 + threadIdx.x;
    if (idx < T_ * HID_ * D_) {
        int t = idx / (HID_ * D_), rem = idx % (HID_ * D_);
        int h = rem / D_, d = rem % D_;
        W1T[idx] = f2bu(W1[(t * D_ + d) * HID_ + h]);
    } else {
        int j = idx - T_ * HID_ * D_;
        int t = j / (D_ * HID_), rem = j % (D_ * HID_);
        int d = rem / HID_, h = rem % HID_;
        W2T[j] = f2bu(W2[(t * HID_ + h) * D_ + d]);
    }
}

// ---------------------------------------------------------------------------
// Prep: ori[b][n][d] -> oriT[b][d][n] bf16, and out[b][n][64+d] = ori (fp32)
// ---------------------------------------------------------------------------
__global__ __launch_bounds__(256) void k_ori_prep(const float* __restrict__ ori,
                                                  float* __restrict__ out,
                                                  unsigned short* __restrict__ oriT) {
    int b = blockIdx.y, n0 = blockIdx.x * 64;
    __shared__ float tl[64 * 65];
    int tid = threadIdx.x;
    int dl = tid & 63;
    #pragma unroll 4
    for (int p = 0; p < 16; ++p) {
        int nn = p * 4 + (tid >> 6);
        float v = ori[(size_t)(b * N_ + n0 + nn) * D_ + dl];
        out[(size_t)(b * N_ + n0 + nn) * 128 + 64 + dl] = v;
        tl[dl * 65 + nn] = v;
    }
    __syncthreads();
    #pragma unroll 4
    for (int p = 0; p < 16; ++p) {
        int dd = p * 4 + (tid >> 6);
        oriT[(size_t)(b * D_ + dd) * N_ + n0 + dl] = f2bu(tl[dd * 65 + dl]);
    }
}

// ---------------------------------------------------------------------------
// Fused K1+K2, v6 (resubmit of R5 — container infra failure, no kernel defect
// found on audit):
//   Phase 1: R0's 2-barrier loop with R2's validated unpadded XOR-swizzle
//     staging (bank conflicts 4.4M -> 0.33M measured in R2); the already-
//     converted bf16 H tile is ALSO stored to Hbf[b][e][n] so k_gemm_out can
//     read 64MB bf16 instead of 134MB fp32 (identical RNE values).
//   Phase 2: R0-VERBATIM (measured 88.6us, best so far).
// ---------------------------------------------------------------------------
__global__ __launch_bounds__(256) void k_edge_mlp(const float* __restrict__ H,
                                                  const unsigned short* __restrict__ oriT,
                                                  const float* __restrict__ ed,
                                                  const float* __restrict__ b1,
                                                  const float* __restrict__ b2,
                                                  const unsigned short* __restrict__ W1T,
                                                  const unsigned short* __restrict__ W2T,
                                                  unsigned short* __restrict__ efT,
                                                  unsigned short* __restrict__ Hbf) {
    int bx = blockIdx.x;
    int b = bx >> 4, e0 = (bx & 15) * 64;
    __shared__ __align__(16) unsigned short aA[64 * 64];     // H-tile, swizzled
    __shared__ __align__(16) unsigned short bB[64 * 64];     // oriT tile, swizzled
    __shared__ __align__(16) unsigned short a_sh[64 * 72];   // edges tile [r][d]
    __shared__ __align__(16) unsigned short w_sh[128 * 72];  // W1T / W2T (aliased)
    __shared__ __align__(16) unsigned short h_sh[64 * 136];  // h' tile [r][hid]
    __shared__ float wd_sh[320];
    __shared__ float b1_sh[640];
    __shared__ float b2_sh[320];
    int tid = threadIdx.x, w = tid >> 6, l = tid & 63, q = l >> 4, c = l & 15;
    int rs = tid >> 3, sgs = tid & 7;
    int swsl = (sgs ^ (rs & 7)) * 8;   // slot(row,colgrp) = colgrp ^ (row&7); rs+32 same &7

    // small staging (visible by first barrier below)
    for (int u = tid; u < 320; u += 256) wd_sh[u] = ed[((size_t)b * E_ + e0) * T_ + u];
    for (int u = tid; u < 640; u += 256) b1_sh[u] = b1[u];
    for (int u = tid; u < 320; u += 256) b2_sh[u] = b2[u];

    const f32x4 zero = {0.f, 0.f, 0.f, 0.f};

    // ---- Phase 1: edges tile GEMM (M=64 e-rows, N=64 d, K=512 n, BK=64) ----
    f32x4 acc1[4];
    #pragma unroll
    for (int fn = 0; fn < 4; ++fn) acc1[fn] = zero;

    const float* Hb = &H[((size_t)b * E_ + e0) * N_];
    const unsigned short* Ob = &oriT[(size_t)b * D_ * N_];

    for (int ks = 0; ks < 8; ++ks) {
        int k0 = ks * 64;
        // stage A: rows rs, rs+32 of H -> bf16 (packed cvt), swizzled slots
        const float* s0 = Hb + (size_t)rs * N_ + k0 + sgs * 8;
        const float* s1 = Hb + (size_t)(rs + 32) * N_ + k0 + sgs * 8;
        float4 f00 = *(const float4*)&s0[0], f01 = *(const float4*)&s0[4];
        float4 f10 = *(const float4*)&s1[0], f11 = *(const float4*)&s1[4];
        uint4 ca = cvt8(f00, f01), cb = cvt8(f10, f11);
        *(uint4*)&aA[rs * 64 + swsl] = ca;
        *(uint4*)&aA[(rs + 32) * 64 + swsl] = cb;
        // stage B: oriT rows (bf16, n-contig), swizzled slots
        *(uint4*)&bB[rs * 64 + swsl] =
            *(const uint4*)&Ob[(size_t)rs * N_ + k0 + sgs * 8];
        *(uint4*)&bB[(rs + 32) * 64 + swsl] =
            *(const uint4*)&Ob[(size_t)(rs + 32) * N_ + k0 + sgs * 8];
        // bf16 H copy for k_gemm_out (identical RNE values; fire-and-forget)
        if (Hbf) {
            *(uint4*)&Hbf[((size_t)b * E_ + e0 + rs) * N_ + k0 + sgs * 8] = ca;
            *(uint4*)&Hbf[((size_t)b * E_ + e0 + rs + 32) * N_ + k0 + sgs * 8] = cb;
        }
        __syncthreads();
        #pragma unroll
        for (int hh = 0; hh < 2; ++hh) {
            int sl = ((hh * 4 + q) ^ (c & 7)) * 8;
            bf16x8 a0 = *(const bf16x8*)&aA[(w * 16 + c) * 64 + sl];
            #pragma unroll
            for (int fn = 0; fn < 4; ++fn) {
                bf16x8 bb = *(const bf16x8*)&bB[(fn * 16 + c) * 64 + sl];
                acc1[fn] = MFMA16(a0, bb, acc1[fn]);
            }
        }
        __syncthreads();
    }
    // C-layout -> a_sh[r][d] (bf16), same quantization point as R0
    #pragma unroll
    for (int fn = 0; fn < 4; ++fn)
        #pragma unroll
        for (int i = 0; i < 4; ++i)
            a_sh[(w * 16 + q * 4 + i) * 72 + fn * 16 + c] = f2bu(acc1[fn][i]);
    // visibility handled by B0 barrier at top of t-loop

    // ---- Phase 2: per-type MLP + mixture (R0-verbatim) ----
    f32x4 y[4];
    #pragma unroll
    for (int fn = 0; fn < 4; ++fn) y[fn] = zero;

    for (int t = 0; t < T_; ++t) {
        __syncthreads();  // B0: a_sh/wd/b1/b2 visible; prev GEMM2 done with w_sh/h_sh
        #pragma unroll
        for (int p = 0; p < 4; ++p) {  // W1T[t]: 128 rows x 64 bf16 = 1024 uint4
            int u = p * 256 + tid, hh = u >> 3, sg = u & 7;
            *(uint4*)&w_sh[hh * 72 + sg * 8] =
                *(const uint4*)&W1T[(t * HID_ + hh) * D_ + sg * 8];
        }
        __syncthreads();  // B1
        f32x4 hc[8];
        #pragma unroll
        for (int fn = 0; fn < 8; ++fn) hc[fn] = zero;
        #pragma unroll
        for (int ks = 0; ks < 2; ++ks) {
            bf16x8 a = *(const bf16x8*)&a_sh[(w * 16 + c) * 72 + ks * 32 + q * 8];
            #pragma unroll
            for (int fn = 0; fn < 8; ++fn) {
                bf16x8 bb = *(const bf16x8*)&w_sh[(fn * 16 + c) * 72 + ks * 32 + q * 8];
                hc[fn] = MFMA16(a, bb, hc[fn]);
            }
        }
        float wv[4];
        #pragma unroll
        for (int i = 0; i < 4; ++i) wv[i] = wd_sh[(w * 16 + q * 4 + i) * T_ + t];
        #pragma unroll
        for (int fn = 0; fn < 8; ++fn) {
            float b1v = b1_sh[t * HID_ + fn * 16 + c];
            #pragma unroll
            for (int i = 0; i < 4; ++i) {
                float v = hc[fn][i] + b1v;
                v = fmaxf(v, 0.0f) * wv[i];
                h_sh[(w * 16 + q * 4 + i) * 136 + fn * 16 + c] = f2bu(v);
            }
        }
        __syncthreads();  // B2: GEMM1 w_sh reads + h_sh writes complete
        #pragma unroll
        for (int p = 0; p < 4; ++p) {  // W2T[t]: 64 rows x 128 bf16 = 1024 uint4
            int u = p * 256 + tid, dd = u >> 4, sg = u & 15;
            *(uint4*)&w_sh[dd * 136 + sg * 8] =
                *(const uint4*)&W2T[(t * D_ + dd) * HID_ + sg * 8];
        }
        __syncthreads();  // B3
        #pragma unroll
        for (int ks = 0; ks < 4; ++ks) {
            bf16x8 a = *(const bf16x8*)&h_sh[(w * 16 + c) * 136 + ks * 32 + q * 8];
            #pragma unroll
            for (int fn = 0; fn < 4; ++fn) {
                bf16x8 bb = *(const bf16x8*)&w_sh[(fn * 16 + c) * 136 + ks * 32 + q * 8];
                y[fn] = MFMA16(a, bb, y[fn]);
            }
        }
    }
    // epilogue: + sum_t w*b2, write efT[b][d][e] transposed (bf16 ushort4)
    #pragma unroll
    for (int fn = 0; fn < 4; ++fn) {
        int d = fn * 16 + c;
        ushort4 o;
        #pragma unroll
        for (int i = 0; i < 4; ++i) {
            int r = w * 16 + q * 4 + i;
            float s = y[fn][i];
            #pragma unroll
            for (int t = 0; t < T_; ++t) s += wd_sh[r * T_ + t] * b2_sh[t * D_ + d];
            ((unsigned short*)&o)[i] = f2bu(s);
        }
        *(ushort4*)&efT[((size_t)b * D_ + d) * E_ + e0 + w * 16 + q * 4] = o;
    }
}

// ---------------------------------------------------------------------------
// K3: out[b][n][d] = sum_e H[b][e][n] * ef[b][e][d] as outT tile.
// Ping-pong double-buffered K-loop + XCD swizzle (R4, proven). When Hbf is
// available, B-stage reads bf16 (16B/row vs 64B/row fp32) and interleaves
// e-pairs in-register (identical RNE values as the pack2 path).
// ---------------------------------------------------------------------------
__global__ __launch_bounds__(256) void k_gemm_out(const float* __restrict__ H,
                                                  const unsigned short* __restrict__ Hbf,
                                                  const unsigned short* __restrict__ efT,
                                                  float* __restrict__ out) {
    int bid = blockIdx.x;
    int swz = (bid & 7) * 64 + (bid >> 3);    // 512 % 8 == 0 -> bijective
    int b = swz >> 3, n0 = (swz & 7) * 64;
    __shared__ __align__(16) unsigned short aA[2][64 * 72];   // efT [d][e]
    __shared__ unsigned int bB32[2][64 * 33];                 // H^T [n][e/2] pair-packed
    int tid = threadIdx.x, w = tid >> 6, l = tid & 63, q = l >> 4, c = l & 15;
    int r2 = tid >> 3, cg = tid & 7;
    const f32x4 zero = {0.f, 0.f, 0.f, 0.f};
    f32x4 acc[4];
    #pragma unroll
    for (int fm = 0; fm < 4; ++fm) acc[fm] = zero;

    const unsigned short* Ab = &efT[(size_t)b * D_ * E_];

    if (Hbf) {
        const unsigned short* Hb2 = &Hbf[(size_t)b * E_ * N_ + n0];
        union U8 { uint4 u; unsigned short s[8]; };
        uint4 ar0, ar1;
        U8 ha, hb;
        {   // prologue: ks=0 loads
            ar0 = *(const uint4*)&Ab[(size_t)r2 * E_ + cg * 8];
            ar1 = *(const uint4*)&Ab[(size_t)(r2 + 32) * E_ + cg * 8];
            ha.u = *(const uint4*)&Hb2[(size_t)(2 * r2) * N_ + cg * 8];
            hb.u = *(const uint4*)&Hb2[(size_t)(2 * r2 + 1) * N_ + cg * 8];
        }
        {   // write buf0
            *(uint4*)&aA[0][r2 * 72 + cg * 8] = ar0;
            *(uint4*)&aA[0][(r2 + 32) * 72 + cg * 8] = ar1;
            #pragma unroll
            for (int j = 0; j < 8; ++j)
                bB32[0][(cg * 8 + j) * 33 + r2] =
                    (unsigned int)ha.s[j] | ((unsigned int)hb.s[j] << 16);
        }
        __syncthreads();
        for (int ks = 0; ks < 16; ++ks) {
            if (ks < 15) {  // issue next-step loads before compute
                int k0 = (ks + 1) * 64;
                ar0 = *(const uint4*)&Ab[(size_t)r2 * E_ + k0 + cg * 8];
                ar1 = *(const uint4*)&Ab[(size_t)(r2 + 32) * E_ + k0 + cg * 8];
                ha.u = *(const uint4*)&Hb2[(size_t)(k0 + 2 * r2) * N_ + cg * 8];
                hb.u = *(const uint4*)&Hb2[(size_t)(k0 + 2 * r2 + 1) * N_ + cg * 8];
            }
            int cur = ks & 1;
            #pragma unroll
            for (int hh = 0; hh < 2; ++hh) {
                union { unsigned int u[4]; bf16x8 v; } bb;
                #pragma unroll
                for (int i = 0; i < 4; ++i)
                    bb.u[i] = bB32[cur][(w * 16 + c) * 33 + hh * 16 + q * 4 + i];
                #pragma unroll
                for (int fm = 0; fm < 4; ++fm) {
                    bf16x8 afr = *(const bf16x8*)&aA[cur][(fm * 16 + c) * 72 + hh * 32 + q * 8];
                    acc[fm] = MFMA16(afr, bb.v, acc[fm]);
                }
            }
            if (ks < 15) {
                int nxt = cur ^ 1;
                *(uint4*)&aA[nxt][r2 * 72 + cg * 8] = ar0;
                *(uint4*)&aA[nxt][(r2 + 32) * 72 + cg * 8] = ar1;
                #pragma unroll
                for (int j = 0; j < 8; ++j)
                    bB32[nxt][(cg * 8 + j) * 33 + r2] =
                        (unsigned int)ha.s[j] | ((unsigned int)hb.s[j] << 16);
                __syncthreads();
            }
        }
    } else {
        const float* Hb = &H[(size_t)b * E_ * N_ + n0];
        uint4 ar0, ar1;
        float4 f0, f1, g0, g1;
        {   // prologue: ks=0 loads
            ar0 = *(const uint4*)&Ab[(size_t)r2 * E_ + cg * 8];
            ar1 = *(const uint4*)&Ab[(size_t)(r2 + 32) * E_ + cg * 8];
            const float* s0 = Hb + (size_t)(2 * r2) * N_ + cg * 8;
            const float* s1 = s0 + N_;
            f0 = *(const float4*)&s0[0]; f1 = *(const float4*)&s0[4];
            g0 = *(const float4*)&s1[0]; g1 = *(const float4*)&s1[4];
        }
        {   // write buf0
            *(uint4*)&aA[0][r2 * 72 + cg * 8] = ar0;
            *(uint4*)&aA[0][(r2 + 32) * 72 + cg * 8] = ar1;
            float r0a[8] = {f0.x, f0.y, f0.z, f0.w, f1.x, f1.y, f1.z, f1.w};
            float r1a[8] = {g0.x, g0.y, g0.z, g0.w, g1.x, g1.y, g1.z, g1.w};
            #pragma unroll
            for (int j = 0; j < 8; ++j)
                bB32[0][(cg * 8 + j) * 33 + r2] = pack2(r0a[j], r1a[j]);
        }
        __syncthreads();
        for (int ks = 0; ks < 16; ++ks) {
            if (ks < 15) {
                int k0 = (ks + 1) * 64;
                ar0 = *(const uint4*)&Ab[(size_t)r2 * E_ + k0 + cg * 8];
                ar1 = *(const uint4*)&Ab[(size_t)(r2 + 32) * E_ + k0 + cg * 8];
                const float* s0 = Hb + (size_t)(k0 + 2 * r2) * N_ + cg * 8;
                const float* s1 = s0 + N_;
                f0 = *(const float4*)&s0[0]; f1 = *(const float4*)&s0[4];
                g0 = *(const float4*)&s1[0]; g1 = *(const float4*)&s1[4];
            }
            int cur = ks & 1;
            #pragma unroll
            for (int hh = 0; hh < 2; ++hh) {
                union { unsigned int u[4]; bf16x8 v; } bb;
                #pragma unroll
                for (int i = 0; i < 4; ++i)
                    bb.u[i] = bB32[cur][(w * 16 + c) * 33 + hh * 16 + q * 4 + i];
                #pragma unroll
                for (int fm = 0; fm < 4; ++fm) {
                    bf16x8 afr = *(const bf16x8*)&aA[cur][(fm * 16 + c) * 72 + hh * 32 + q * 8];
                    acc[fm] = MFMA16(afr, bb.v, acc[fm]);
                }
            }
            if (ks < 15) {
                int nxt = cur ^ 1;
                *(uint4*)&aA[nxt][r2 * 72 + cg * 8] = ar0;
                *(uint4*)&aA[nxt][(r2 + 32) * 72 + cg * 8] = ar1;
                float r0a[8] = {f0.x, f0.y, f0.z, f0.w, f1.x, f1.y, f1.z, f1.w};
                float r1a[8] = {g0.x, g0.y, g0.z, g0.w, g1.x, g1.y, g1.z, g1.w};
                #pragma unroll
                for (int j = 0; j < 8; ++j)
                    bB32[nxt][(cg * 8 + j) * 33 + r2] = pack2(r0a[j], r1a[j]);
                __syncthreads();
            }
        }
    }
    #pragma unroll
    for (int fm = 0; fm < 4; ++fm) {
        *(f32x4*)&out[((size_t)b * N_ + n0 + w * 16 + c) * 128 + fm * 16 + q * 4] = acc[fm];
    }
}

// ---------------------------------------------------------------------------
extern "C" void kernel_launch(void* const* d_in, const int* in_sizes, int n_in,
                              void* d_out, int out_size, void* d_ws, size_t ws_size,
                              hipStream_t stream) {
    const float* ed  = (const float*)d_in[0];  // [B,E,T]
    const float* H   = (const float*)d_in[1];  // [B,E,N]
    const float* ori = (const float*)d_in[2];  // [B,N,64]
    const float* W1  = (const float*)d_in[3];  // [T,64,128]
    const float* b1  = (const float*)d_in[4];  // [T,128]
    const float* W2  = (const float*)d_in[5];  // [T,128,64]
    const float* b2  = (const float*)d_in[6];  // [T,64]
    float* out = (float*)d_out;

    char* ws = (char*)d_ws;
    size_t used = 0;
    unsigned short* oriT = (unsigned short*)(ws + used); used += (size_t)B_ * D_ * N_ * 2;   // 4 MB
    unsigned short* W1T  = (unsigned short*)(ws + used); used += (size_t)T_ * HID_ * D_ * 2;
    unsigned short* W2T  = (unsigned short*)(ws + used); used += (size_t)T_ * D_ * HID_ * 2;
    unsigned short* efT  = (unsigned short*)(ws + used); used += (size_t)B_ * D_ * E_ * 2;   // 8 MB
    size_t hbf_bytes = (size_t)B_ * E_ * N_ * 2;                                             // 64 MB
    unsigned short* Hbf = nullptr;
    if (ws_size >= used + hbf_bytes) {
        Hbf = (unsigned short*)(ws + used);
        used += hbf_bytes;
    }

    hipLaunchKernelGGL(k_prep_w, dim3(320), dim3(256), 0, stream, W1, W2, W1T, W2T);
    hipLaunchKernelGGL(k_ori_prep, dim3(8, 64), dim3(256), 0, stream, ori, out, oriT);
    hipLaunchKernelGGL(k_edge_mlp, dim3(1024), dim3(256), 0, stream,
                       H, oriT, ed, b1, b2, W1T, W2T, efT, Hbf);
    hipLaunchKernelGGL(k_gemm_out, dim3(512), dim3(256), 0, stream, H, Hbf, efT, out);
}